// Round 1
// baseline (672.538 us; speedup 1.0000x reference)
//
#include <hip/hip_runtime.h>

// FocalLossAdaptive: per-row log_softmax at target index, adaptive gamma, sum.
// N=4096 rows, C=32000 cols fp32. Memory-bound: 524 MB single read.
// One 256-thread block per row; online softmax (single pass, float4 loads).

#define BLOCK 256

__global__ __launch_bounds__(BLOCK) void focal_loss_adaptive_kernel(
    const float* __restrict__ input,
    const int* __restrict__ target,
    float* __restrict__ out,
    int C) {
  const int row = blockIdx.x;
  const int tid = threadIdx.x;
  const float* __restrict__ rowp = input + (size_t)row * (size_t)C;

  // Online softmax accumulation: running max m, running sum s of exp(x - m).
  float m = -3.402823466e+38f;
  float s = 0.0f;

  const int nvec = C >> 2;  // float4 vectors per row
  const float4* __restrict__ row4 = reinterpret_cast<const float4*>(rowp);
  for (int i = tid; i < nvec; i += BLOCK) {
    float4 v = row4[i];
#pragma unroll
    for (int k = 0; k < 4; ++k) {
      float x = (&v.x)[k];
      if (x > m) {            // rare (~log(elems/thread) times per thread)
        s *= __expf(m - x);
        m = x;
      }
      s += __expf(x - m);
    }
  }
  // scalar tail (C % 4)
  for (int i = (nvec << 2) + tid; i < C; i += BLOCK) {
    float x = rowp[i];
    if (x > m) { s *= __expf(m - x); m = x; }
    s += __expf(x - m);
  }

  // Wave-level (64-lane) reduction of the (m, s) pair.
#pragma unroll
  for (int off = 32; off > 0; off >>= 1) {
    float mo = __shfl_down(m, off);
    float so = __shfl_down(s, off);
    float M = fmaxf(m, mo);
    s = s * __expf(m - M) + so * __expf(mo - M);
    m = M;
  }

  // Cross-wave combine via LDS (BLOCK/64 = 4 waves).
  __shared__ float sm[BLOCK / 64];
  __shared__ float ss[BLOCK / 64];
  const int wave = tid >> 6;
  const int lane = tid & 63;
  if (lane == 0) { sm[wave] = m; ss[wave] = s; }
  __syncthreads();

  if (tid == 0) {
    const int nw = BLOCK / 64;
    float M = sm[0];
#pragma unroll
    for (int w = 1; w < nw; ++w) M = fmaxf(M, sm[w]);
    float S = 0.0f;
#pragma unroll
    for (int w = 0; w < nw; ++w) S += ss[w] * __expf(sm[w] - M);

    const int t = target[row];
    const float xt = rowp[t];          // re-read; L1/L2-hot
    const float logpt = xt - M - logf(S);
    const float pt = __expf(logpt);
    const float om = 1.0f - pt;
    const float w3 = om * om * om;
    // gamma: pt >= 0.5 -> 3; pt < 0.2 -> 5; else -> 3  ==>  (pt<0.2) ? 5 : 3
    const float wgt = (pt < 0.2f) ? w3 * om * om : w3;
    atomicAdd(out, -wgt * logpt);
  }
}

extern "C" void kernel_launch(void* const* d_in, const int* in_sizes, int n_in,
                              void* d_out, int out_size, void* d_ws, size_t ws_size,
                              hipStream_t stream) {
  const float* input = (const float*)d_in[0];
  const int* target = (const int*)d_in[1];
  float* out = (float*)d_out;

  const int N = in_sizes[1];            // 4096 rows
  const int C = in_sizes[0] / N;        // 32000 cols

  // d_out is poisoned 0xAA before every timed launch; zero it (capturable).
  hipMemsetAsync(out, 0, (size_t)out_size * sizeof(float), stream);

  focal_loss_adaptive_kernel<<<dim3(N), dim3(BLOCK), 0, stream>>>(input, target, out, C);
}

// Round 2
// 670.375 us; speedup vs baseline: 1.0032x; 1.0032x over previous
//
#include <hip/hip_runtime.h>
#include <float.h>

// FocalLossAdaptive: per-row log_softmax at target index, adaptive gamma, sum.
// N=4096 rows, C=32000 cols fp32. Memory-bound: 524 MB single HBM read.
// One 256-thread block per row; single-pass online softmax with 8-element
// chunking: local chunk-max (no loop-carried dep) + one branchless merge
// per chunk => 8x less loop-carried work, ~1.1 exp/element instead of ~2.

#define BLOCK 256

__global__ __launch_bounds__(BLOCK) void focal_loss_adaptive_kernel(
    const float* __restrict__ input,
    const int* __restrict__ target,
    float* __restrict__ out,
    int C) {
  const int row = blockIdx.x;
  const int tid = threadIdx.x;
  const float* __restrict__ rowp = input + (size_t)row * (size_t)C;

  float m = -FLT_MAX;
  float s = 0.0f;

  const int nchunk = C >> 3;  // 8-element chunks (two float4 loads)
  const float4* __restrict__ row4 = reinterpret_cast<const float4*>(rowp);
  for (int i = tid; i < nchunk; i += BLOCK) {
    float4 a = row4[2 * i];
    float4 b = row4[2 * i + 1];
    // chunk max: independent fmax tree (compiler folds to v_max3)
    float c = fmaxf(fmaxf(fmaxf(a.x, a.y), fmaxf(a.z, a.w)),
                    fmaxf(fmaxf(b.x, b.y), fmaxf(b.z, b.w)));
    // 8 independent exps vs chunk max
    float e = __expf(a.x - c) + __expf(a.y - c) +
              __expf(a.z - c) + __expf(a.w - c) +
              __expf(b.x - c) + __expf(b.y - c) +
              __expf(b.z - c) + __expf(b.w - c);
    // branchless merge of (c,e) into running (m,s): exactly one exp
    float M = fmaxf(m, c);
    float d = __expf(fminf(m, c) - M);  // first iter: exp(-inf)=0, s=0*0+e=e
    s = (c > m) ? fmaf(s, d, e) : fmaf(e, d, s);
    m = M;
  }
  // scalar tail (C % 8; none for C=32000 but keep generic)
  for (int i = (nchunk << 3) + tid; i < C; i += BLOCK) {
    float x = rowp[i];
    float M = fmaxf(m, x);
    float d = __expf(fminf(m, x) - M);
    s = (x > m) ? fmaf(s, d, 1.0f) : s + d;
    m = M;
  }

  // Wave-level (64-lane) pairwise merge of (m, s).
#pragma unroll
  for (int off = 32; off > 0; off >>= 1) {
    float mo = __shfl_down(m, off);
    float so = __shfl_down(s, off);
    float M = fmaxf(m, mo);
    s = s * __expf(m - M) + so * __expf(mo - M);
    m = M;
  }

  // Cross-wave combine via LDS (BLOCK/64 = 4 waves).
  __shared__ float sm[BLOCK / 64];
  __shared__ float ss[BLOCK / 64];
  const int wave = tid >> 6;
  const int lane = tid & 63;
  if (lane == 0) { sm[wave] = m; ss[wave] = s; }
  __syncthreads();

  if (tid == 0) {
    const int nw = BLOCK / 64;
    float M = sm[0];
#pragma unroll
    for (int w = 1; w < nw; ++w) M = fmaxf(M, sm[w]);
    float S = 0.0f;
#pragma unroll
    for (int w = 0; w < nw; ++w) S += ss[w] * __expf(sm[w] - M);

    const int t = target[row];
    const float xt = rowp[t];          // re-read; L2-hot
    const float logpt = xt - M - __logf(S);
    const float pt = __expf(logpt);
    const float om = 1.0f - pt;
    const float w3 = om * om * om;
    // gamma: pt >= 0.5 -> 3; pt < 0.2 -> 5; else -> 3  ==>  (pt<0.2) ? 5 : 3
    const float wgt = (pt < 0.2f) ? w3 * om * om : w3;
    atomicAdd(out, -wgt * logpt);
  }
}

extern "C" void kernel_launch(void* const* d_in, const int* in_sizes, int n_in,
                              void* d_out, int out_size, void* d_ws, size_t ws_size,
                              hipStream_t stream) {
  const float* input = (const float*)d_in[0];
  const int* target = (const int*)d_in[1];
  float* out = (float*)d_out;

  const int N = in_sizes[1];            // 4096 rows
  const int C = in_sizes[0] / N;        // 32000 cols

  // d_out is poisoned 0xAA before every timed launch; zero it (capturable).
  hipMemsetAsync(out, 0, (size_t)out_size * sizeof(float), stream);

  focal_loss_adaptive_kernel<<<dim3(N), dim3(BLOCK), 0, stream>>>(input, target, out, C);
}

// Round 3
// 666.313 us; speedup vs baseline: 1.0093x; 1.0061x over previous
//
#include <hip/hip_runtime.h>
#include <float.h>

// FocalLossAdaptive: per-row log_softmax at target, adaptive gamma, summed.
// N=4096 rows, C=32000 cols fp32. Memory-bound: 524 MB single HBM read.
// Stage 1: one 256-thread block per row, single-pass online softmax with
//   8-element chunks; per-row loss -> plain store to ws[row].
//   (R2 post-mortem: a single-address atomicAdd from 4096 blocks serialized
//    at the coherence point and dominated the kernel; stores don't.)
// Stage 2: one block reduces ws[0..N) -> out[0].

#define BLOCK 256

__global__ __launch_bounds__(BLOCK) void focal_row_kernel(
    const float* __restrict__ input,
    const int* __restrict__ target,
    float* __restrict__ row_loss,
    int C) {
  const int row = blockIdx.x;
  const int tid = threadIdx.x;
  const float* __restrict__ rowp = input + (size_t)row * (size_t)C;

  float m = -FLT_MAX;
  float s = 0.0f;

  const int nchunk = C >> 3;  // 8-element chunks (two float4 loads)
  const float4* __restrict__ row4 = reinterpret_cast<const float4*>(rowp);
  for (int i = tid; i < nchunk; i += BLOCK) {
    float4 a = row4[2 * i];
    float4 b = row4[2 * i + 1];
    float c = fmaxf(fmaxf(fmaxf(a.x, a.y), fmaxf(a.z, a.w)),
                    fmaxf(fmaxf(b.x, b.y), fmaxf(b.z, b.w)));
    float e = __expf(a.x - c) + __expf(a.y - c) +
              __expf(a.z - c) + __expf(a.w - c) +
              __expf(b.x - c) + __expf(b.y - c) +
              __expf(b.z - c) + __expf(b.w - c);
    float M = fmaxf(m, c);
    float d = __expf(fminf(m, c) - M);  // first iter: exp(-inf)=0
    s = (c > m) ? fmaf(s, d, e) : fmaf(e, d, s);
    m = M;
  }
  for (int i = (nchunk << 3) + tid; i < C; i += BLOCK) {  // generic tail
    float x = rowp[i];
    float M = fmaxf(m, x);
    float d = __expf(fminf(m, x) - M);
    s = (x > m) ? fmaf(s, d, 1.0f) : s + d;
    m = M;
  }

  // Wave-level (64-lane) pairwise merge of (m, s).
#pragma unroll
  for (int off = 32; off > 0; off >>= 1) {
    float mo = __shfl_down(m, off);
    float so = __shfl_down(s, off);
    float M = fmaxf(m, mo);
    s = s * __expf(m - M) + so * __expf(mo - M);
    m = M;
  }

  __shared__ float sm[BLOCK / 64];
  __shared__ float ss[BLOCK / 64];
  const int wave = tid >> 6;
  const int lane = tid & 63;
  if (lane == 0) { sm[wave] = m; ss[wave] = s; }
  __syncthreads();

  if (tid == 0) {
    const int nw = BLOCK / 64;
    float M = sm[0];
#pragma unroll
    for (int w = 1; w < nw; ++w) M = fmaxf(M, sm[w]);
    float S = 0.0f;
#pragma unroll
    for (int w = 0; w < nw; ++w) S += ss[w] * __expf(sm[w] - M);

    const int t = target[row];
    const float xt = rowp[t];          // L2-hot re-read
    const float logpt = xt - M - __logf(S);
    const float pt = __expf(logpt);
    const float om = 1.0f - pt;
    const float w3 = om * om * om;
    // gamma: pt >= 0.5 -> 3; pt < 0.2 -> 5; else -> 3  ==> (pt<0.2) ? 5 : 3
    const float wgt = (pt < 0.2f) ? w3 * om * om : w3;
    row_loss[row] = -wgt * logpt;      // plain store; no atomic contention
  }
}

__global__ __launch_bounds__(BLOCK) void reduce_kernel(
    const float* __restrict__ row_loss, float* __restrict__ out, int N) {
  const int tid = threadIdx.x;
  float s = 0.0f;
  for (int i = tid; i < N; i += BLOCK) s += row_loss[i];
#pragma unroll
  for (int off = 32; off > 0; off >>= 1) s += __shfl_down(s, off);
  __shared__ float sw[BLOCK / 64];
  if ((tid & 63) == 0) sw[tid >> 6] = s;
  __syncthreads();
  if (tid == 0) out[0] = sw[0] + sw[1] + sw[2] + sw[3];
}

extern "C" void kernel_launch(void* const* d_in, const int* in_sizes, int n_in,
                              void* d_out, int out_size, void* d_ws, size_t ws_size,
                              hipStream_t stream) {
  const float* input = (const float*)d_in[0];
  const int* target = (const int*)d_in[1];
  float* out = (float*)d_out;
  float* row_loss = (float*)d_ws;      // N floats of scratch

  const int N = in_sizes[1];            // 4096 rows
  const int C = in_sizes[0] / N;        // 32000 cols

  focal_row_kernel<<<dim3(N), dim3(BLOCK), 0, stream>>>(input, target, row_loss, C);
  reduce_kernel<<<dim3(1), dim3(BLOCK), 0, stream>>>(row_loss, out, N);
}

// Round 4
// 662.328 us; speedup vs baseline: 1.0154x; 1.0060x over previous
//
#include <hip/hip_runtime.h>
#include <float.h>

// FocalLossAdaptive: per-row log_softmax at target, adaptive gamma, summed.
// N=4096 rows, C=32000 cols fp32. Memory-bound: 524 MB single HBM read.
// Stage 1: one 256-thread block per row. Each thread runs FOUR independent
//   online-softmax streams (m[j],s[j]) over 8-element chunks so 8 float4
//   loads are in flight with no loop-carried dependence between them
//   (R3 post-mortem: testing the MLP-limited hypothesis — prior rounds
//   showed arithmetic density and atomics are not the limiter).
// Stage 2: one block reduces ws[0..N) -> out[0].

#define BLOCK 256
#define NSTR 4

__device__ __forceinline__ void merge_chunk(float& m, float& s, float c, float e) {
  // branchless merge of chunk (c, e) into running (m, s); exactly one exp.
  float M = fmaxf(m, c);
  float d = __expf(fminf(m, c) - M);   // m = -FLT_MAX: d = 0, s = e
  s = (c > m) ? fmaf(s, d, e) : fmaf(e, d, s);
  m = M;
}

__global__ __launch_bounds__(BLOCK) void focal_row_kernel(
    const float* __restrict__ input,
    const int* __restrict__ target,
    float* __restrict__ row_loss,
    int C) {
  const int row = blockIdx.x;
  const int tid = threadIdx.x;
  const float* __restrict__ rowp = input + (size_t)row * (size_t)C;
  const float4* __restrict__ row4 = reinterpret_cast<const float4*>(rowp);

  float m[NSTR], s[NSTR];
#pragma unroll
  for (int j = 0; j < NSTR; ++j) { m[j] = -FLT_MAX; s[j] = 0.0f; }

  const int nchunk = C >> 3;  // 8-element chunks (two float4 loads each)
  int k = tid;
  // Main loop: NSTR independent chunks per trip; all loads issue together.
  for (; k + (NSTR - 1) * BLOCK < nchunk; k += NSTR * BLOCK) {
    float4 a[NSTR], b[NSTR];
#pragma unroll
    for (int j = 0; j < NSTR; ++j) {
      a[j] = row4[2 * (k + j * BLOCK)];
      b[j] = row4[2 * (k + j * BLOCK) + 1];
    }
#pragma unroll
    for (int j = 0; j < NSTR; ++j) {
      float c = fmaxf(fmaxf(fmaxf(a[j].x, a[j].y), fmaxf(a[j].z, a[j].w)),
                      fmaxf(fmaxf(b[j].x, b[j].y), fmaxf(b[j].z, b[j].w)));
      float e = __expf(a[j].x - c) + __expf(a[j].y - c) +
                __expf(a[j].z - c) + __expf(a[j].w - c) +
                __expf(b[j].x - c) + __expf(b[j].y - c) +
                __expf(b[j].z - c) + __expf(b[j].w - c);
      merge_chunk(m[j], s[j], c, e);
    }
  }
  // Remainder chunks -> stream 0.
  for (; k < nchunk; k += BLOCK) {
    float4 a = row4[2 * k];
    float4 b = row4[2 * k + 1];
    float c = fmaxf(fmaxf(fmaxf(a.x, a.y), fmaxf(a.z, a.w)),
                    fmaxf(fmaxf(b.x, b.y), fmaxf(b.z, b.w)));
    float e = __expf(a.x - c) + __expf(a.y - c) +
              __expf(a.z - c) + __expf(a.w - c) +
              __expf(b.x - c) + __expf(b.y - c) +
              __expf(b.z - c) + __expf(b.w - c);
    merge_chunk(m[0], s[0], c, e);
  }
  // Scalar tail elements (C % 8; none for C=32000 but keep generic).
  for (int i = (nchunk << 3) + tid; i < C; i += BLOCK) {
    float x = rowp[i];
    merge_chunk(m[0], s[0], x, 1.0f);
  }

  // Merge the NSTR streams.
#pragma unroll
  for (int j = 1; j < NSTR; ++j) {
    float M = fmaxf(m[0], m[j]);
    float d = __expf(fminf(m[0], m[j]) - M);
    s[0] = (m[j] > m[0]) ? fmaf(s[0], d, s[j]) : fmaf(s[j], d, s[0]);
    m[0] = M;
  }
  float mm = m[0], ss = s[0];

  // Wave-level (64-lane) pairwise merge of (mm, ss).
#pragma unroll
  for (int off = 32; off > 0; off >>= 1) {
    float mo = __shfl_down(mm, off);
    float so = __shfl_down(ss, off);
    float M = fmaxf(mm, mo);
    ss = ss * __expf(mm - M) + so * __expf(mo - M);
    mm = M;
  }

  __shared__ float sm[BLOCK / 64];
  __shared__ float sw[BLOCK / 64];
  const int wave = tid >> 6;
  const int lane = tid & 63;
  if (lane == 0) { sm[wave] = mm; sw[wave] = ss; }
  __syncthreads();

  if (tid == 0) {
    const int nw = BLOCK / 64;
    float M = sm[0];
#pragma unroll
    for (int w = 1; w < nw; ++w) M = fmaxf(M, sm[w]);
    float S = 0.0f;
#pragma unroll
    for (int w = 0; w < nw; ++w) S += sw[w] * __expf(sm[w] - M);

    const int t = target[row];
    const float xt = rowp[t];          // L2-hot re-read
    const float logpt = xt - M - __logf(S);
    const float pt = __expf(logpt);
    const float om = 1.0f - pt;
    const float w3 = om * om * om;
    // gamma: pt >= 0.5 -> 3; pt < 0.2 -> 5; else -> 3  ==> (pt<0.2) ? 5 : 3
    const float wgt = (pt < 0.2f) ? w3 * om * om : w3;
    row_loss[row] = -wgt * logpt;      // plain store; no atomic contention
  }
}

__global__ __launch_bounds__(BLOCK) void reduce_kernel(
    const float* __restrict__ row_loss, float* __restrict__ out, int N) {
  const int tid = threadIdx.x;
  float s = 0.0f;
  for (int i = tid; i < N; i += BLOCK) s += row_loss[i];
#pragma unroll
  for (int off = 32; off > 0; off >>= 1) s += __shfl_down(s, off);
  __shared__ float sw[BLOCK / 64];
  if ((tid & 63) == 0) sw[tid >> 6] = s;
  __syncthreads();
  if (tid == 0) out[0] = sw[0] + sw[1] + sw[2] + sw[3];
}

extern "C" void kernel_launch(void* const* d_in, const int* in_sizes, int n_in,
                              void* d_out, int out_size, void* d_ws, size_t ws_size,
                              hipStream_t stream) {
  const float* input = (const float*)d_in[0];
  const int* target = (const int*)d_in[1];
  float* out = (float*)d_out;
  float* row_loss = (float*)d_ws;      // N floats of scratch

  const int N = in_sizes[1];            // 4096 rows
  const int C = in_sizes[0] / N;        // 32000 cols

  focal_row_kernel<<<dim3(N), dim3(BLOCK), 0, stream>>>(input, target, row_loss, C);
  reduce_kernel<<<dim3(1), dim3(BLOCK), 0, stream>>>(row_loss, out, N);
}